// Round 10
// baseline (191.999 us; speedup 1.0000x reference)
//
#include <hip/hip_runtime.h>
#include <hip/hip_bf16.h>

// MultiHeadSelfAttention: B=2, S=2048, D=1024, H=16, Dh=64, RoPE theta=1e4, causal.
// Round 20: FUSE combine INTO out_proj. Key: out_proj's K-step (64) == HDIM, so
// the A-tile at K-step `it` is exactly combine's output for (qt, head=it).
// A-staging becomes: load nsplit Opart uint4s + Lpart (issued one iter early),
// vmcnt(0) at iter top (free: loads had a full MFMA phase), unpack+normalize+
// pack, ds_write with the XOR swizzle frag reads expect. B (Wo) keeps DMA.
// Removes combine dispatch + launch gap + AO HBM round trip (5 kernels -> 4).
// attn (R19 swizzled), qkv (R16), conv unchanged.
// ws (u16): Q|K|Vt|AO(=Xbf)|Wbf (40MB) + Opart 2560x4096 u16 (21MB) + Lpart (0.7MB).

#define D_MODEL 1024
#define NHEADS  16
#define HDIM    64
#define SEQ     2048
#define BATCH   2

typedef unsigned short u16;
typedef __bf16 bf16x8_t __attribute__((ext_vector_type(8)));
typedef float  f32x4_t  __attribute__((ext_vector_type(4)));

__device__ __forceinline__ u16 f2bf(float f) {
    union { __hip_bfloat16 h; u16 u; } cv;
    cv.h = __float2bfloat16(f);
    return cv.u;
}

__device__ __forceinline__ unsigned pk2(float x, float y) {
    union { __hip_bfloat162 h; unsigned u; } cv;
    cv.h = __float22bfloat162_rn(make_float2(x, y));   // v_cvt_pk_bf16_f32
    return cv.u;
}

__device__ __forceinline__ uint4 pack8(float4 a, float4 b) {
    uint4 u;
    u.x = pk2(a.x, a.y);
    u.y = pk2(a.z, a.w);
    u.z = pk2(b.x, b.y);
    u.w = pk2(b.z, b.w);
    return u;
}

__device__ __forceinline__ bf16x8_t frag_ld(const u16* p) {
    union { uint4 u; bf16x8_t v; } t;
    t.u = *(const uint4*)p;
    return t.v;
}

// unpack 4 bf16-pairs (uint4) -> add into 8 fp32 accumulators
__device__ __forceinline__ void acc8(uint4 u, float* a) {
    a[0] += __uint_as_float(u.x << 16); a[1] += __uint_as_float(u.x & 0xffff0000u);
    a[2] += __uint_as_float(u.y << 16); a[3] += __uint_as_float(u.y & 0xffff0000u);
    a[4] += __uint_as_float(u.z << 16); a[5] += __uint_as_float(u.z & 0xffff0000u);
    a[6] += __uint_as_float(u.w << 16); a[7] += __uint_as_float(u.w & 0xffff0000u);
}

// async global->LDS DMA, 16B/lane; LDS dest = wave-uniform base + lane*16
__device__ __forceinline__ void dma16(const u16* g, u16* l) {
    __builtin_amdgcn_global_load_lds(
        (const __attribute__((address_space(1))) void*)g,
        (__attribute__((address_space(3))) void*)l, 16, 0, 0);
}

// ---------------------------------------------------------------------------
// fp32 -> bf16 conversion: X (4M elems) -> Xbf, Wq|Wk|Wv|Wo (1M each) -> Wbf.
// ---------------------------------------------------------------------------
__global__ __launch_bounds__(256) void conv_bf16_kernel(
    const float* __restrict__ X, const float* __restrict__ Wq,
    const float* __restrict__ Wk, const float* __restrict__ Wv,
    const float* __restrict__ Wo, u16* __restrict__ Xbf, u16* __restrict__ Wbf)
{
    const size_t gid = (size_t)blockIdx.x * 256 + threadIdx.x;
    const float* src;
    u16* dst;
    size_t off;
    if (gid < (1u << 19)) {                     // X: 4M elems / 8
        src = X; dst = Xbf; off = gid;
    } else {
        size_t g = gid - (1u << 19);
        const int wsel = (int)(g >> 17);        // 1M elems / 8 per W
        g &= (1u << 17) - 1;
        src = (wsel == 0) ? Wq : (wsel == 1) ? Wk : (wsel == 2) ? Wv : Wo;
        dst = Wbf + ((size_t)wsel << 20);
        off = g;
    }
    const float4 a = *(const float4*)(src + off * 8);
    const float4 b = *(const float4*)(src + off * 8 + 4);
    *(uint4*)(dst + off * 8) = pack8(a, b);
}

// ---------------------------------------------------------------------------
// QKV projection + RoPE. R16: 2-phase double-buffered staging with counted
// vmcnt(8); Ts overlays staging after the K-loop. Unchanged.
// ---------------------------------------------------------------------------
__global__ __launch_bounds__(256) void qkv_rope_kernel(
    const u16* __restrict__ Xbf, const u16* __restrict__ Wbf,
    const int* __restrict__ pos,
    u16* __restrict__ Qo, u16* __restrict__ Ko, u16* __restrict__ Vt)
{
    __shared__ __align__(16) u16 smem[32768];   // 64KB: A0|A1|B0|B1 (8192 u16 each)
                                                // Ts 128x132 overlays after K-loop
    const int tid = threadIdx.x;
    const int m0 = blockIdx.y * 128;
    const int nv = blockIdx.x * 128;
    const int which = nv >> 10;                 // 0=q,1=k,2=v
    const int nbase = nv & 1023;
    const u16* __restrict__ Wsrc = Wbf + ((size_t)which << 20);

    const int w = tid >> 6, L = tid & 63, quad = L >> 4, colL = L & 15;
    const int mw = (w & 1) * 64, nw = (w >> 1) * 64;

    const int lrow = L >> 3;
    const int lchk = (L & 7) ^ lrow;            // XOR chunk swizzle
    const u16* ag = Xbf + (size_t)(m0 + 32 * w + lrow) * D_MODEL + lchk * 8;
    const u16* bg = Wsrc + (size_t)(nbase + 32 * w + lrow) * D_MODEL + lchk * 8;

    f32x4_t acc[4][4];
    #pragma unroll
    for (int i = 0; i < 4; ++i)
        #pragma unroll
        for (int j = 0; j < 4; ++j) acc[i][j] = (f32x4_t){0.f, 0.f, 0.f, 0.f};

    // stage tile k0 (elems) into buffer boff (0 or 8192)
    #define QKV_STAGE(boff, k0)                                                 \
        {                                                                       \
            u16* al = smem + (boff) + (32 * w) * 64;                            \
            u16* bl = smem + 16384 + (boff) + (32 * w) * 64;                    \
            _Pragma("unroll")                                                   \
            for (int j = 0; j < 4; ++j) {                                       \
                dma16(ag + (size_t)j * 8 * D_MODEL + (k0), al + j * 512);       \
                dma16(bg + (size_t)j * 8 * D_MODEL + (k0), bl + j * 512);       \
            }                                                                   \
        }

    QKV_STAGE(0, 0)                             // prologue: tile 0 -> buf 0
    for (int it = 0; it < 16; ++it) {
        const int boff = (it & 1) << 13;        // buffer being computed
        if (it < 15) {
            QKV_STAGE(boff ^ 8192, (it + 1) * 64)   // next tile -> other buffer
            asm volatile("s_waitcnt vmcnt(8)" ::: "memory");  // prev stage landed
        } else {
            asm volatile("s_waitcnt vmcnt(0)" ::: "memory");
        }
        __builtin_amdgcn_sched_barrier(0);
        __builtin_amdgcn_s_barrier();           // all waves' stages visible
        __builtin_amdgcn_sched_barrier(0);

        const u16* a_s = smem + boff;
        const u16* b_s = smem + 16384 + boff;
        #pragma unroll
        for (int kb = 0; kb < 2; ++kb) {
            const int ch = ((kb * 4 + quad) ^ (colL & 7)) * 8;
            bf16x8_t af[4], bf[4];
            #pragma unroll
            for (int t = 0; t < 4; ++t) {
                af[t] = frag_ld(a_s + (mw + t * 16 + colL) * 64 + ch);
                bf[t] = frag_ld(b_s + (nw + t * 16 + colL) * 64 + ch);
            }
            #pragma unroll
            for (int mt = 0; mt < 4; ++mt)
                #pragma unroll
                for (int nt = 0; nt < 4; ++nt)
                    acc[mt][nt] = __builtin_amdgcn_mfma_f32_16x16x32_bf16(
                        af[mt], bf[nt], acc[mt][nt], 0, 0, 0);
        }
        __builtin_amdgcn_s_barrier();           // buffer free for next stage
    }

    __syncthreads();
    u16 (*Ts)[132] = (u16(*)[132])smem;

    const float C0 = 0.14391156831212787f;      // ln(10000)/64
    if (which < 2) {
        // Q scale = (1/sqrt(64)) * log2(e): attn uses exp2 directly
        const float oscale = (which == 0) ? 0.18033688011112042f : 1.0f;
        float invf[4], sgn[4];
        #pragma unroll
        for (int nt = 0; nt < 4; ++nt) {
            const int n = nbase + nw + nt * 16 + colL;
            const int dd = n & 63;
            invf[nt] = __expf(-(float)(dd & 62) * C0);
            sgn[nt] = (dd & 1) ? 1.0f : -1.0f;
        }
        #pragma unroll
        for (int mt = 0; mt < 4; ++mt) {
            #pragma unroll
            for (int r = 0; r < 4; ++r) {
                const int ml = mw + mt * 16 + quad * 4 + r;
                const int ss = (m0 + ml) & 2047;
                const float p = (float)pos[ss];
                #pragma unroll
                for (int nt = 0; nt < 4; ++nt) {
                    const float v = acc[mt][nt][r];
                    const float partner = __shfl_xor(v, 1);
                    float sn, cs;
                    __sincosf(p * invf[nt], &sn, &cs);
                    Ts[ml][nw + nt * 16 + colL] =
                        f2bf((v * cs + sgn[nt] * sn * partner) * oscale);
                }
            }
        }
    } else {
        #pragma unroll
        for (int mt = 0; mt < 4; ++mt)
            #pragma unroll
            for (int nt = 0; nt < 4; ++nt)
                #pragma unroll
                for (int r = 0; r < 4; ++r)
                    Ts[nw + nt * 16 + colL][mw + mt * 16 + quad * 4 + r] = f2bf(acc[mt][nt][r]);
    }
    __syncthreads();

    const int rr0 = tid >> 4;
    const int cc8 = (tid & 15) * 8;
    if (which < 2) {
        u16* __restrict__ dst = (which == 0) ? Qo : Ko;
        #pragma unroll
        for (int it = 0; it < 8; ++it) {
            const int ml = rr0 + it * 16;
            const int m = m0 + ml, bb = m >> 11, ss = m & 2047;
            const int n = nbase + cc8, h = n >> 6, d = n & 63;
            *(uint4*)&dst[((size_t)(bb * NHEADS + h) * SEQ + ss) * HDIM + d] =
                *(const uint4*)&Ts[ml][cc8];
        }
    } else {
        const int bb = m0 >> 11, ss0 = (m0 & 2047) + cc8;
        #pragma unroll
        for (int it = 0; it < 8; ++it) {
            const int nl = rr0 + it * 16;
            const int n = nbase + nl, h = n >> 6, d = n & 63;
            *(uint4*)&Vt[((size_t)(bb * NHEADS + h) * HDIM + d) * SEQ + ss0] =
                *(const uint4*)&Ts[nl][cc8];
        }
    }
}

// ---------------------------------------------------------------------------
// Split-K flash attention (causal, max-free). R19: pitch-64 swizzled LDS.
// Unchanged from round 19.
// ---------------------------------------------------------------------------
__global__ __launch_bounds__(256) void attn_kernel(
    const u16* __restrict__ Q, const u16* __restrict__ K,
    const u16* __restrict__ Vt, u16* __restrict__ Opart, float* __restrict__ Lpart)
{
    __shared__ __align__(16) u16 Ks[64][64];    // [key][d], chunk-swizzled
    __shared__ __align__(16) u16 Vs[64][64];    // [d][key], chunk-swizzled
    __shared__ __align__(16) u16 Ps[4][16][64]; // per-wave [q_local][key], swizzled

    const int tid = threadIdx.x;
    const int slot = 79 - (int)blockIdx.x;      // LPT: deepest chunks first
    const int g = (slot >= 48) ? 3 : (slot >= 24) ? 2 : (slot >= 8) ? 1 : 0;
    const int t0 = slot - 4 * g * (g + 1);
    const int rr = t0 / (g + 1);
    const int s  = t0 - rr * (g + 1);
    const int qt = 8 * g + rr;

    const int hh = blockIdx.y, bb = blockIdx.z;
    const size_t bh = ((size_t)bb * NHEADS + hh) * (SEQ * HDIM);
    const int q0 = qt * 64;
    const int kt0 = s * 8;
    const int ktend = min(kt0 + 8, qt + 1);
    const size_t gslot = ((size_t)(bb * NHEADS + hh) * 80 + slot);

    const int w = tid >> 6, L = tid & 63, quad = L >> 4, colL = L & 15;
    const int srow = tid >> 2, sc = (tid & 3) * 16;
    const int c7 = colL & 7;                    // row&7 for frag reads
    // staging dest chunks (swizzled): source chunks (L&3)*2 and (L&3)*2+1
    const int sch0 = (((tid & 3) * 2) ^ (srow & 7)) * 8;
    const int sch1 = (((tid & 3) * 2 + 1) ^ (srow & 7)) * 8;

    // Q fragments in registers (pre-scaled by log2e/8 in qkv): q = w*16+colL
    const u16* qp = Q + bh + (size_t)(q0 + w * 16 + colL) * HDIM + quad * 8;
    const bf16x8_t aq0 = frag_ld(qp);           // d = 0..31 slice (kb=0)
    const bf16x8_t aq1 = frag_ld(qp + 32);      // d = 32..63 slice (kb=1)

    float lsum = 0.f;                           // per-lane, q = w*16 + colL
    f32x4_t O[4];
    #pragma unroll
    for (int dt = 0; dt < 4; ++dt) O[dt] = (f32x4_t){0.f, 0.f, 0.f, 0.f};

    // prefetch first tile of this chunk
    const u16* kp = K + bh + (size_t)(kt0 * 64 + srow) * HDIM + sc;
    const u16* vp = Vt + bh + (size_t)srow * SEQ + kt0 * 64 + sc;
    uint4 kv0 = *(const uint4*)kp;
    uint4 kv1 = *(const uint4*)(kp + 8);
    uint4 vv0 = *(const uint4*)vp;
    uint4 vv1 = *(const uint4*)(vp + 8);

    for (int kt = kt0; kt < ktend; ++kt) {
        __builtin_amdgcn_s_barrier();           // all waves done READING prev tile
        asm volatile("s_waitcnt vmcnt(0)" ::: "memory");   // prefetch landed (hidden under prev compute)
        __builtin_amdgcn_sched_barrier(0);
        *(uint4*)&Ks[srow][sch0] = kv0;
        *(uint4*)&Ks[srow][sch1] = kv1;
        *(uint4*)&Vs[srow][sch0] = vv0;
        *(uint4*)&Vs[srow][sch1] = vv1;
        if (kt + 1 < ktend) {                   // prefetch next tile; stays in flight
            const int k1 = (kt + 1) * 64;       // across the barrier below
            const u16* kpn = K + bh + (size_t)(k1 + srow) * HDIM + sc;
            kv0 = *(const uint4*)kpn;
            kv1 = *(const uint4*)(kpn + 8);
            const u16* vpn = Vt + bh + (size_t)srow * SEQ + k1 + sc;
            vv0 = *(const uint4*)vpn;
            vv1 = *(const uint4*)(vpn + 8);
        }
        asm volatile("s_waitcnt lgkmcnt(0)" ::: "memory"); // own ds_writes done
        __builtin_amdgcn_sched_barrier(0);
        __builtin_amdgcn_s_barrier();           // all waves' stages visible

        const bool diag = (kt == qt);
        const int ntmax = diag ? w : 3;         // wave-uniform causal pruning
        const int kbmax = diag ? (w >> 1) : 1;

        // S^T = K·Q^T: S[nt][r] = score(key = nt*16+quad*4+r, q = w*16+colL)
        // swizzled chunks: kb0 -> quad^c7, kb1 -> (quad^4)^c7
        f32x4_t S[4];
        #pragma unroll
        for (int nt = 0; nt < 4; ++nt) S[nt] = (f32x4_t){0.f, 0.f, 0.f, 0.f};
        #pragma unroll
        for (int nt = 0; nt < 4; ++nt) {
            if (nt <= ntmax) {
                S[nt] = __builtin_amdgcn_mfma_f32_16x16x32_bf16(
                    frag_ld(&Ks[nt * 16 + colL][(quad ^ c7) * 8]), aq0, S[nt], 0, 0, 0);
                S[nt] = __builtin_amdgcn_mfma_f32_16x16x32_bf16(
                    frag_ld(&Ks[nt * 16 + colL][((quad ^ 4) ^ c7) * 8]), aq1, S[nt], 0, 0, 0);
            }
        }

        // max-free: p = exp2(s) (log2e pre-folded); lane holds 4 consecutive
        // keys per nt => pack pairs, one ds_write_b64 per nt (swizzled chunk).
        if (!diag) {                            // clean path: no masking (94% of tiles)
            #pragma unroll
            for (int nt = 0; nt < 4; ++nt) {
                const float p0 = __builtin_amdgcn_exp2f(S[nt][0]);
                const float p1 = __builtin_amdgcn_exp2f(S[nt][1]);
                const float p2 = __builtin_amdgcn_exp2f(S[nt][2]);
                const float p3 = __builtin_amdgcn_exp2f(S[nt][3]);
                lsum += (p0 + p1) + (p2 + p3);
                uint2 pw;
                pw.x = pk2(p0, p1);
                pw.y = pk2(p2, p3);
                *(uint2*)&Ps[w][colL][((2 * nt + (quad >> 1)) ^ c7) * 8 + (quad & 1) * 4] = pw;
            }
        } else {
            const int qrel = w * 16 + colL;     // q - qt*64
            #pragma unroll
            for (int nt = 0; nt < 4; ++nt) {
                float p0 = 0.f, p1 = 0.f, p2 = 0.f, p3 = 0.f;
                if (nt <= ntmax) {              // wave-uniform scalar branch
                    const int krel = nt * 16 + quad * 4;
                    p0 = (krel + 0 <= qrel) ? __builtin_amdgcn_exp2f(S[nt][0]) : 0.f;
                    p1 = (krel + 1 <= qrel) ? __builtin_amdgcn_exp2f(S[nt][1]) : 0.f;
                    p2 = (krel + 2 <= qrel) ? __builtin_amdgcn_exp2f(S[nt][2]) : 0.f;
                    p3 = (krel + 3 <= qrel) ? __builtin_amdgcn_exp2f(S[nt][3]) : 0.f;
                }
                lsum += (p0 + p1) + (p2 + p3);
                uint2 pw;
                pw.x = pk2(p0, p1);
                pw.y = pk2(p2, p3);
                *(uint2*)&Ps[w][colL][((2 * nt + (quad >> 1)) ^ c7) * 8 + (quad & 1) * 4] = pw;
            }
        }

        asm volatile("s_waitcnt lgkmcnt(0)" ::: "memory");  // wave-local Ps ready
        __builtin_amdgcn_sched_barrier(0);

        // PV: static unroll, wave-uniform kb predication; swizzled chunks.
        #pragma unroll
        for (int kb = 0; kb < 2; ++kb) {
            if (kb <= kbmax) {
                const int ch = ((kb * 4 + quad) ^ c7) * 8;
                const bf16x8_t ap = frag_ld(&Ps[w][colL][ch]);
                #pragma unroll
                for (int dt = 0; dt < 4; ++dt) {
                    const bf16x8_t bv = frag_ld(&Vs[dt * 16 + colL][ch]);
                    O[dt] = __builtin_amdgcn_mfma_f32_16x16x32_bf16(ap, bv, O[dt], 0, 0, 0);
                }
            }
        }
    }

    // l partial: q = w*16 + colL; sum the 4 quads holding the same q
    {
        float sm = lsum;
        sm += __shfl_xor(sm, 16);
        sm += __shfl_xor(sm, 32);
        if (quad == 0)
            Lpart[gslot * 64 + 16 * w + colL] = sm;
    }

    // O partial (unnormalized bf16): C-layout -> per-wave LDS (swizzled) ->
    // coalesced stores
    #pragma unroll
    for (int dt = 0; dt < 4; ++dt)
        #pragma unroll
        for (int r = 0; r < 4; ++r) {
            const int row = quad * 4 + r;
            const int ch = ((2 * dt + (colL >> 3)) ^ (row & 7)) * 8 + (colL & 7);
            Ps[w][row][ch] = f2bf(O[dt][r]);
        }
    asm volatile("s_waitcnt lgkmcnt(0)" ::: "memory");
    __builtin_amdgcn_sched_barrier(0);
    #pragma unroll
    for (int p = 0; p < 2; ++p) {
        const int rowl = (L >> 3) + 8 * p;      // 0..15
        const int ch = ((L & 7) ^ (rowl & 7)) * 8;
        *(uint4*)&Opart[gslot * 4096 + (size_t)(16 * w + rowl) * 64 + (L & 7) * 8] =
            *(const uint4*)&Ps[w][rowl][ch];
    }
}

// ---------------------------------------------------------------------------
// Output projection FUSED with combine: Out = (combine(Opart,Lpart)) * Wo^T.
// K-step 64 == HDIM: A-tile at step `it` = combine output for (qt, head=it).
// A-staging: nsplit Opart uint4s + Lpart loaded into regs one iter early
// (consume-then-issue, vmcnt(0) free at iter top), unpack+normalize+pack,
// ds_write with XOR swizzle. B (Wo) stays on the DMA path. 64x128 tile,
// 512 blocks (2/CU), LDS 48KB.
// ---------------------------------------------------------------------------
__global__ __launch_bounds__(256) void out_proj_kernel(
    const u16* __restrict__ Opart, const float* __restrict__ Lpart,
    const u16* __restrict__ Wob, float* __restrict__ Out)
{
    __shared__ __align__(16) u16 smem[24576];   // 48KB: 2 bufs x (A 64x64 | B 128x64)

    const int tid = threadIdx.x;
    const int m0 = blockIdx.y * 64;             // M = 4096 -> 64 tiles
    const int n0 = blockIdx.x * 128;            // N = 1024 -> 8 tiles

    const int w = tid >> 6, L = tid & 63, quad = L >> 4, colL = L & 15;
    const int mw = (w & 1) * 32, nw = (w >> 1) * 64;

    const int lrow = L >> 3;
    const int lchk = (L & 7) ^ lrow;            // XOR chunk swizzle (B staging)

    // combine geometry (wave-uniform): all 64 rows share one qt
    const int bb = m0 >> 11;
    const int qt = (m0 & 2047) >> 6;
    const int cg_ = qt >> 3;
    const int nsplit = cg_ + 1;
    const int base = 4 * cg_ * (cg_ + 1) + (qt & 7) * (cg_ + 1);
    const int bb16 = bb * NHEADS;

    const u16* bg = Wob + (size_t)(n0 + 32 * w + lrow) * D_MODEL + lchk * 8;

    f32x4_t acc[2][4];
    #pragma unroll
    for (int i = 0; i < 2; ++i)
        #pragma unroll
        for (int j = 0; j < 4; ++j) acc[i][j] = (f32x4_t){0.f, 0.f, 0.f, 0.f};

    uint4 ldo[2][4];                            // in-flight Opart slices
    float ldl[2][4];                            // in-flight Lpart

    // issue A-combine loads for head `hs`: thread chunk c -> (q, col-group)
    #define A_ISSUE(hs)                                                         \
        {                                                                       \
            const size_t slot0 = ((size_t)(bb16 + (hs))) * 80 + base;           \
            _Pragma("unroll")                                                   \
            for (int c = 0; c < 2; ++c) {                                       \
                const int slot = tid + 256 * c;                                 \
                const int q = slot >> 3, cg = slot & 7;                         \
                _Pragma("unroll")                                               \
                for (int s = 0; s < 4; ++s) {                                   \
                    if (s < nsplit) {                                           \
                        const size_t gs = slot0 + s;                            \
                        ldo[c][s] = *(const uint4*)(Opart + gs * 4096 +         \
                                                    (size_t)q * 64 + cg * 8);   \
                        ldl[c][s] = Lpart[gs * 64 + q];                         \
                    }                                                           \
                }                                                               \
            }                                                                   \
        }

    // consume regs: combine + normalize + pack -> swizzled ds_write into buf
    #define A_WRITE(boff)                                                       \
        {                                                                       \
            _Pragma("unroll")                                                   \
            for (int c = 0; c < 2; ++c) {                                       \
                const int slot = tid + 256 * c;                                 \
                const int q = slot >> 3, cg = slot & 7;                         \
                float o[8];                                                     \
                _Pragma("unroll")                                               \
                for (int i = 0; i < 8; ++i) o[i] = 0.f;                         \
                float l = 0.f;                                                  \
                _Pragma("unroll")                                               \
                for (int s = 0; s < 4; ++s)                                     \
                    if (s < nsplit) { acc8(ldo[c][s], o); l += ldl[c][s]; }     \
                const float inv = 1.0f / l;                                     \
                uint4 pw;                                                       \
                pw.x = pk2(o[0] * inv, o[1] * inv);                             \
                pw.y = pk2(o[2] * inv, o[3] * inv);                             \
                pw.z = pk2(o[4] * inv, o[5] * inv);                             \
                pw.w = pk2(o[6] * inv, o[7] * inv);                             \
                *(uint4*)&smem[(boff) + q * 64 + ((cg ^ (q & 7)) * 8)] = pw;    \
            }                                                                   \
        }

    // B staging (Wo rows n0..n0+127) via DMA into buf+4096
    #define B_ISSUE(boff, k0)                                                   \
        {                                                                       \
            u16* bl = smem + (boff) + 4096 + (32 * w) * 64;                     \
            _Pragma("unroll")                                                   \
            for (int j = 0; j < 4; ++j)                                         \
                dma16(bg + (size_t)j * 8 * D_MODEL + (k0), bl + j * 512);       \
        }

    A_ISSUE(0)
    B_ISSUE(0, 0)
    for (int it = 0; it < 16; ++it) {
        const int boff = (it & 1) * 12288;
        asm volatile("s_waitcnt vmcnt(0)" ::: "memory");   // A regs + B DMA landed
        __builtin_amdgcn_sched_barrier(0);                 // (issued one iter ago)
        A_WRITE(boff)
        if (it < 15) {
            A_ISSUE(it + 1)
            B_ISSUE(boff ^ 12288, (it + 1) * 64)
        }
        asm volatile("s_waitcnt lgkmcnt(0)" ::: "memory"); // own A ds_writes done
        __builtin_amdgcn_sched_barrier(0);
        __builtin_amdgcn_s_barrier();
        __builtin_amdgcn_sched_barrier(0);

        const u16* a_s = smem + boff;           // A 64x64 (combined, swizzled)
        const u16* b_s = smem + boff + 4096;    // B 128x64
        #pragma unroll
        for (int kb = 0; kb < 2; ++kb) {
            const int ch = ((kb * 4 + quad) ^ (colL & 7)) * 8;
            bf16x8_t af[2], bf[4];
            #pragma unroll
            for (int t = 0; t < 2; ++t)
                af[t] = frag_ld(a_s + (mw + t * 16 + colL) * 64 + ch);
            #pragma unroll
            for (int t = 0; t < 4; ++t)
                bf[t] = frag_ld(b_s + (nw + t * 16 + colL) * 64 + ch);
            #pragma unroll
            for (int mt = 0; mt < 2; ++mt)
                #pragma unroll
                for (int nt = 0; nt < 4; ++nt)
                    acc[mt][nt] = __builtin_amdgcn_mfma_f32_16x16x32_bf16(
                        af[mt], bf[nt], acc[mt][nt], 0, 0, 0);
        }
        __builtin_amdgcn_s_barrier();
    }

    #pragma unroll
    for (int mt = 0; mt < 2; ++mt)
        #pragma unroll
        for (int nt = 0; nt < 4; ++nt)
            #pragma unroll
            for (int r = 0; r < 4; ++r) {
                const int m = m0 + mw + mt * 16 + quad * 4 + r;
                const int n = n0 + nw + nt * 16 + colL;
                Out[(size_t)m * D_MODEL + n] = acc[mt][nt][r];
            }
}

// ---------------------------------------------------------------------------
extern "C" void kernel_launch(void* const* d_in, const int* in_sizes, int n_in,
                              void* d_out, int out_size, void* d_ws, size_t ws_size,
                              hipStream_t stream) {
    const float* x  = (const float*)d_in[0];
    const float* wq = (const float*)d_in[1];
    const float* wk = (const float*)d_in[2];
    const float* wv = (const float*)d_in[3];
    const float* wo = (const float*)d_in[4];
    const int* pos  = (const int*)d_in[5];
    float* out = (float*)d_out;

    const size_t NELEM = (size_t)BATCH * NHEADS * SEQ * HDIM;  // 4,194,304
    u16* Qw  = (u16*)d_ws;
    u16* Kw  = Qw + NELEM;
    u16* Vtw = Kw + NELEM;
    u16* AOw = Vtw + NELEM;        // = Xbf (combine fused away; region only Xbf now)
    u16* Xbf = AOw;
    u16* Wbf = AOw + NELEM;        // 4M elems (wq|wk|wv|wo)
    u16* Opart = Wbf + NELEM;      // 2560 slots x 4096 u16 = 21MB
    float* Lpart = (float*)(Opart + (size_t)2560 * 4096);  // 2560 x 64 fp32

    conv_bf16_kernel<<<4096, 256, 0, stream>>>(x, wq, wk, wv, wo, Xbf, Wbf);
    qkv_rope_kernel<<<dim3(24, 32), 256, 0, stream>>>(Xbf, Wbf, pos, Qw, Kw, Vtw);
    attn_kernel<<<dim3(80, NHEADS, BATCH), 256, 0, stream>>>(Qw, Kw, Vtw, Opart, Lpart);
    out_proj_kernel<<<dim3(8, 64), 256, 0, stream>>>(Opart, Lpart, Wbf + 3 * (1u << 20), out);
}

// Round 11
// 183.903 us; speedup vs baseline: 1.0440x; 1.0440x over previous
//
#include <hip/hip_runtime.h>
#include <hip/hip_bf16.h>

// MultiHeadSelfAttention: B=2, S=2048, D=1024, H=16, Dh=64, RoPE theta=1e4, causal.
// Round 21: revert R20 fusion (confounded regression; qkv jumped 46->55 with
// identical code = codegen coupling, rule #19). Back to R19 (185.0 best) with
// ONE change: qkv tile 128x128 -> 128x64. LDS 64->48KB => 2->3 blocks/CU
// (occupancy was 15%, everything idle: latency-bound with too few waves).
// Grid 24x32 -> 48x32; 6 dma16/thread, vmcnt(6); acc 4x2; Ts overlay
// [128][68] (q/k) / [64][136] (V). attn/combine/out_proj/conv = R19 exact.
// ws (u16): Q|K|Vt|AO(=Xbf)|Wbf (40MB) + Opart 2560x4096 u16 (21MB) + Lpart (0.7MB).

#define D_MODEL 1024
#define NHEADS  16
#define HDIM    64
#define SEQ     2048
#define BATCH   2

typedef unsigned short u16;
typedef __bf16 bf16x8_t __attribute__((ext_vector_type(8)));
typedef float  f32x4_t  __attribute__((ext_vector_type(4)));

__device__ __forceinline__ u16 f2bf(float f) {
    union { __hip_bfloat16 h; u16 u; } cv;
    cv.h = __float2bfloat16(f);
    return cv.u;
}

__device__ __forceinline__ unsigned pk2(float x, float y) {
    union { __hip_bfloat162 h; unsigned u; } cv;
    cv.h = __float22bfloat162_rn(make_float2(x, y));   // v_cvt_pk_bf16_f32
    return cv.u;
}

__device__ __forceinline__ uint4 pack8(float4 a, float4 b) {
    uint4 u;
    u.x = pk2(a.x, a.y);
    u.y = pk2(a.z, a.w);
    u.z = pk2(b.x, b.y);
    u.w = pk2(b.z, b.w);
    return u;
}

__device__ __forceinline__ bf16x8_t frag_ld(const u16* p) {
    union { uint4 u; bf16x8_t v; } t;
    t.u = *(const uint4*)p;
    return t.v;
}

// unpack 4 bf16-pairs (uint4) -> add into 8 fp32 accumulators
__device__ __forceinline__ void acc8(uint4 u, float* a) {
    a[0] += __uint_as_float(u.x << 16); a[1] += __uint_as_float(u.x & 0xffff0000u);
    a[2] += __uint_as_float(u.y << 16); a[3] += __uint_as_float(u.y & 0xffff0000u);
    a[4] += __uint_as_float(u.z << 16); a[5] += __uint_as_float(u.z & 0xffff0000u);
    a[6] += __uint_as_float(u.w << 16); a[7] += __uint_as_float(u.w & 0xffff0000u);
}

// async global->LDS DMA, 16B/lane; LDS dest = wave-uniform base + lane*16
__device__ __forceinline__ void dma16(const u16* g, u16* l) {
    __builtin_amdgcn_global_load_lds(
        (const __attribute__((address_space(1))) void*)g,
        (__attribute__((address_space(3))) void*)l, 16, 0, 0);
}

// ---------------------------------------------------------------------------
// fp32 -> bf16 conversion: X (4M elems) -> Xbf, Wq|Wk|Wv|Wo (1M each) -> Wbf.
// ---------------------------------------------------------------------------
__global__ __launch_bounds__(256) void conv_bf16_kernel(
    const float* __restrict__ X, const float* __restrict__ Wq,
    const float* __restrict__ Wk, const float* __restrict__ Wv,
    const float* __restrict__ Wo, u16* __restrict__ Xbf, u16* __restrict__ Wbf)
{
    const size_t gid = (size_t)blockIdx.x * 256 + threadIdx.x;
    const float* src;
    u16* dst;
    size_t off;
    if (gid < (1u << 19)) {                     // X: 4M elems / 8
        src = X; dst = Xbf; off = gid;
    } else {
        size_t g = gid - (1u << 19);
        const int wsel = (int)(g >> 17);        // 1M elems / 8 per W
        g &= (1u << 17) - 1;
        src = (wsel == 0) ? Wq : (wsel == 1) ? Wk : (wsel == 2) ? Wv : Wo;
        dst = Wbf + ((size_t)wsel << 20);
        off = g;
    }
    const float4 a = *(const float4*)(src + off * 8);
    const float4 b = *(const float4*)(src + off * 8 + 4);
    *(uint4*)(dst + off * 8) = pack8(a, b);
}

// ---------------------------------------------------------------------------
// QKV projection + RoPE. Round 21: 128x64 tile, 48KB LDS (3 blocks/CU),
// 2-phase counted vmcnt(6). A[128][64] + B[64][64] per buffer.
// ---------------------------------------------------------------------------
__global__ __launch_bounds__(256) void qkv_rope_kernel(
    const u16* __restrict__ Xbf, const u16* __restrict__ Wbf,
    const int* __restrict__ pos,
    u16* __restrict__ Qo, u16* __restrict__ Ko, u16* __restrict__ Vt)
{
    __shared__ __align__(16) u16 smem[24576];   // 48KB: 2 bufs x (A 8192 | B 4096)
                                                // Ts [128][68] / [64][136] overlays
    const int tid = threadIdx.x;
    const int m0 = blockIdx.y * 128;
    const int nv = (int)blockIdx.x;             // 0..47
    const int which = nv >> 4;                  // 0=q,1=k,2=v
    const int nbase = (nv & 15) * 64;
    const u16* __restrict__ Wsrc = Wbf + ((size_t)which << 20);

    const int w = tid >> 6, L = tid & 63, quad = L >> 4, colL = L & 15;
    const int mw = (w & 1) * 64, nw = (w >> 1) * 32;

    const int lrow = L >> 3;
    const int lchk = (L & 7) ^ lrow;            // XOR chunk swizzle
    const u16* ag = Xbf + (size_t)(m0 + 32 * w + lrow) * D_MODEL + lchk * 8;
    const u16* bg = Wsrc + (size_t)(nbase + 16 * w + lrow) * D_MODEL + lchk * 8;

    f32x4_t acc[4][2];
    #pragma unroll
    for (int i = 0; i < 4; ++i)
        #pragma unroll
        for (int j = 0; j < 2; ++j) acc[i][j] = (f32x4_t){0.f, 0.f, 0.f, 0.f};

    // stage tile k0 (elems) into buffer boff (0 or 12288): A 4 dma + B 2 dma
    #define QKV_STAGE(boff, k0)                                                 \
        {                                                                       \
            u16* al = smem + (boff) + (32 * w) * 64;                            \
            u16* bl = smem + (boff) + 8192 + (16 * w) * 64;                     \
            _Pragma("unroll")                                                   \
            for (int j = 0; j < 4; ++j)                                         \
                dma16(ag + (size_t)j * 8 * D_MODEL + (k0), al + j * 512);       \
            _Pragma("unroll")                                                   \
            for (int j = 0; j < 2; ++j)                                         \
                dma16(bg + (size_t)j * 8 * D_MODEL + (k0), bl + j * 512);       \
        }

    QKV_STAGE(0, 0)                             // prologue: tile 0 -> buf 0
    for (int it = 0; it < 16; ++it) {
        const int boff = (it & 1) * 12288;      // buffer being computed
        if (it < 15) {
            QKV_STAGE(boff ^ 12288, (it + 1) * 64)  // next tile -> other buffer
            asm volatile("s_waitcnt vmcnt(6)" ::: "memory");  // prev stage landed
        } else {
            asm volatile("s_waitcnt vmcnt(0)" ::: "memory");
        }
        __builtin_amdgcn_sched_barrier(0);
        __builtin_amdgcn_s_barrier();           // all waves' stages visible
        __builtin_amdgcn_sched_barrier(0);

        const u16* a_s = smem + boff;
        const u16* b_s = smem + boff + 8192;
        #pragma unroll
        for (int kb = 0; kb < 2; ++kb) {
            const int ch = ((kb * 4 + quad) ^ (colL & 7)) * 8;
            bf16x8_t af[4], bf[2];
            #pragma unroll
            for (int t = 0; t < 4; ++t)
                af[t] = frag_ld(a_s + (mw + t * 16 + colL) * 64 + ch);
            #pragma unroll
            for (int t = 0; t < 2; ++t)
                bf[t] = frag_ld(b_s + (nw + t * 16 + colL) * 64 + ch);
            #pragma unroll
            for (int mt = 0; mt < 4; ++mt)
                #pragma unroll
                for (int nt = 0; nt < 2; ++nt)
                    acc[mt][nt] = __builtin_amdgcn_mfma_f32_16x16x32_bf16(
                        af[mt], bf[nt], acc[mt][nt], 0, 0, 0);
        }
        __builtin_amdgcn_s_barrier();           // buffer free for next stage
    }

    __syncthreads();
    u16 (*Ts)[68]  = (u16(*)[68])smem;          // q/k: [m 128][n 64]
    u16 (*Ts2)[136] = (u16(*)[136])smem;        // v:   [n 64][m 128]

    const float C0 = 0.14391156831212787f;      // ln(10000)/64
    if (which < 2) {
        // Q scale = (1/sqrt(64)) * log2(e): attn uses exp2 directly
        const float oscale = (which == 0) ? 0.18033688011112042f : 1.0f;
        float invf[2], sgn[2];
        #pragma unroll
        for (int nt = 0; nt < 2; ++nt) {
            const int n = nbase + nw + nt * 16 + colL;
            const int dd = n & 63;
            invf[nt] = __expf(-(float)(dd & 62) * C0);
            sgn[nt] = (dd & 1) ? 1.0f : -1.0f;
        }
        #pragma unroll
        for (int mt = 0; mt < 4; ++mt) {
            #pragma unroll
            for (int r = 0; r < 4; ++r) {
                const int ml = mw + mt * 16 + quad * 4 + r;
                const int ss = (m0 + ml) & 2047;
                const float p = (float)pos[ss];
                #pragma unroll
                for (int nt = 0; nt < 2; ++nt) {
                    const float v = acc[mt][nt][r];
                    const float partner = __shfl_xor(v, 1);
                    float sn, cs;
                    __sincosf(p * invf[nt], &sn, &cs);
                    Ts[ml][nw + nt * 16 + colL] =
                        f2bf((v * cs + sgn[nt] * sn * partner) * oscale);
                }
            }
        }
    } else {
        #pragma unroll
        for (int mt = 0; mt < 4; ++mt)
            #pragma unroll
            for (int nt = 0; nt < 2; ++nt)
                #pragma unroll
                for (int r = 0; r < 4; ++r)
                    Ts2[nw + nt * 16 + colL][mw + mt * 16 + quad * 4 + r] = f2bf(acc[mt][nt][r]);
    }
    __syncthreads();

    const int hh = nbase >> 6;                  // one head per block (BN=64)
    if (which < 2) {
        u16* __restrict__ dst = (which == 0) ? Qo : Ko;
        const int rr0 = tid >> 3;               // 0..31
        const int cc8 = (tid & 7) * 8;          // 0..56
        #pragma unroll
        for (int it = 0; it < 4; ++it) {
            const int ml = rr0 + it * 32;
            const int m = m0 + ml, bb = m >> 11, ss = m & 2047;
            *(uint4*)&dst[((size_t)(bb * NHEADS + hh) * SEQ + ss) * HDIM + cc8] =
                *(const uint4*)&Ts[ml][cc8];
        }
    } else {
        const int rr0 = tid >> 4;               // 0..15
        const int cc8 = (tid & 15) * 8;         // 0..120
        const int bb = m0 >> 11, ss0 = (m0 & 2047) + cc8;
        #pragma unroll
        for (int it = 0; it < 4; ++it) {
            const int nl = rr0 + it * 16;       // d = nl
            *(uint4*)&Vt[((size_t)(bb * NHEADS + hh) * HDIM + nl) * SEQ + ss0] =
                *(const uint4*)&Ts2[nl][cc8];
        }
    }
}

// ---------------------------------------------------------------------------
// Split-K flash attention (causal, max-free). R19: pitch-64 swizzled LDS.
// Unchanged from round 19.
// ---------------------------------------------------------------------------
__global__ __launch_bounds__(256) void attn_kernel(
    const u16* __restrict__ Q, const u16* __restrict__ K,
    const u16* __restrict__ Vt, u16* __restrict__ Opart, float* __restrict__ Lpart)
{
    __shared__ __align__(16) u16 Ks[64][64];    // [key][d], chunk-swizzled
    __shared__ __align__(16) u16 Vs[64][64];    // [d][key], chunk-swizzled
    __shared__ __align__(16) u16 Ps[4][16][64]; // per-wave [q_local][key], swizzled

    const int tid = threadIdx.x;
    const int slot = 79 - (int)blockIdx.x;      // LPT: deepest chunks first
    const int g = (slot >= 48) ? 3 : (slot >= 24) ? 2 : (slot >= 8) ? 1 : 0;
    const int t0 = slot - 4 * g * (g + 1);
    const int rr = t0 / (g + 1);
    const int s  = t0 - rr * (g + 1);
    const int qt = 8 * g + rr;

    const int hh = blockIdx.y, bb = blockIdx.z;
    const size_t bh = ((size_t)bb * NHEADS + hh) * (SEQ * HDIM);
    const int q0 = qt * 64;
    const int kt0 = s * 8;
    const int ktend = min(kt0 + 8, qt + 1);
    const size_t gslot = ((size_t)(bb * NHEADS + hh) * 80 + slot);

    const int w = tid >> 6, L = tid & 63, quad = L >> 4, colL = L & 15;
    const int srow = tid >> 2, sc = (tid & 3) * 16;
    const int c7 = colL & 7;                    // row&7 for frag reads
    // staging dest chunks (swizzled): source chunks (L&3)*2 and (L&3)*2+1
    const int sch0 = (((tid & 3) * 2) ^ (srow & 7)) * 8;
    const int sch1 = (((tid & 3) * 2 + 1) ^ (srow & 7)) * 8;

    // Q fragments in registers (pre-scaled by log2e/8 in qkv): q = w*16+colL
    const u16* qp = Q + bh + (size_t)(q0 + w * 16 + colL) * HDIM + quad * 8;
    const bf16x8_t aq0 = frag_ld(qp);           // d = 0..31 slice (kb=0)
    const bf16x8_t aq1 = frag_ld(qp + 32);      // d = 32..63 slice (kb=1)

    float lsum = 0.f;                           // per-lane, q = w*16 + colL
    f32x4_t O[4];
    #pragma unroll
    for (int dt = 0; dt < 4; ++dt) O[dt] = (f32x4_t){0.f, 0.f, 0.f, 0.f};

    // prefetch first tile of this chunk
    const u16* kp = K + bh + (size_t)(kt0 * 64 + srow) * HDIM + sc;
    const u16* vp = Vt + bh + (size_t)srow * SEQ + kt0 * 64 + sc;
    uint4 kv0 = *(const uint4*)kp;
    uint4 kv1 = *(const uint4*)(kp + 8);
    uint4 vv0 = *(const uint4*)vp;
    uint4 vv1 = *(const uint4*)(vp + 8);

    for (int kt = kt0; kt < ktend; ++kt) {
        __builtin_amdgcn_s_barrier();           // all waves done READING prev tile
        asm volatile("s_waitcnt vmcnt(0)" ::: "memory");   // prefetch landed (hidden under prev compute)
        __builtin_amdgcn_sched_barrier(0);
        *(uint4*)&Ks[srow][sch0] = kv0;
        *(uint4*)&Ks[srow][sch1] = kv1;
        *(uint4*)&Vs[srow][sch0] = vv0;
        *(uint4*)&Vs[srow][sch1] = vv1;
        if (kt + 1 < ktend) {                   // prefetch next tile; stays in flight
            const int k1 = (kt + 1) * 64;       // across the barrier below
            const u16* kpn = K + bh + (size_t)(k1 + srow) * HDIM + sc;
            kv0 = *(const uint4*)kpn;
            kv1 = *(const uint4*)(kpn + 8);
            const u16* vpn = Vt + bh + (size_t)srow * SEQ + k1 + sc;
            vv0 = *(const uint4*)vpn;
            vv1 = *(const uint4*)(vpn + 8);
        }
        asm volatile("s_waitcnt lgkmcnt(0)" ::: "memory"); // own ds_writes done
        __builtin_amdgcn_sched_barrier(0);
        __builtin_amdgcn_s_barrier();           // all waves' stages visible

        const bool diag = (kt == qt);
        const int ntmax = diag ? w : 3;         // wave-uniform causal pruning
        const int kbmax = diag ? (w >> 1) : 1;

        // S^T = K·Q^T: S[nt][r] = score(key = nt*16+quad*4+r, q = w*16+colL)
        // swizzled chunks: kb0 -> quad^c7, kb1 -> (quad^4)^c7
        f32x4_t S[4];
        #pragma unroll
        for (int nt = 0; nt < 4; ++nt) S[nt] = (f32x4_t){0.f, 0.f, 0.f, 0.f};
        #pragma unroll
        for (int nt = 0; nt < 4; ++nt) {
            if (nt <= ntmax) {
                S[nt] = __builtin_amdgcn_mfma_f32_16x16x32_bf16(
                    frag_ld(&Ks[nt * 16 + colL][(quad ^ c7) * 8]), aq0, S[nt], 0, 0, 0);
                S[nt] = __builtin_amdgcn_mfma_f32_16x16x32_bf16(
                    frag_ld(&Ks[nt * 16 + colL][((quad ^ 4) ^ c7) * 8]), aq1, S[nt], 0, 0, 0);
            }
        }

        // max-free: p = exp2(s) (log2e pre-folded); lane holds 4 consecutive
        // keys per nt => pack pairs, one ds_write_b64 per nt (swizzled chunk).
        if (!diag) {                            // clean path: no masking (94% of tiles)
            #pragma unroll
            for (int nt = 0; nt < 4; ++nt) {
                const float p0 = __builtin_amdgcn_exp2f(S[nt][0]);
                const float p1 = __builtin_amdgcn_exp2f(S[nt][1]);
                const float p2 = __builtin_amdgcn_exp2f(S[nt][2]);
                const float p3 = __builtin_amdgcn_exp2f(S[nt][3]);
                lsum += (p0 + p1) + (p2 + p3);
                uint2 pw;
                pw.x = pk2(p0, p1);
                pw.y = pk2(p2, p3);
                *(uint2*)&Ps[w][colL][((2 * nt + (quad >> 1)) ^ c7) * 8 + (quad & 1) * 4] = pw;
            }
        } else {
            const int qrel = w * 16 + colL;     // q - qt*64
            #pragma unroll
            for (int nt = 0; nt < 4; ++nt) {
                float p0 = 0.f, p1 = 0.f, p2 = 0.f, p3 = 0.f;
                if (nt <= ntmax) {              // wave-uniform scalar branch
                    const int krel = nt * 16 + quad * 4;
                    p0 = (krel + 0 <= qrel) ? __builtin_amdgcn_exp2f(S[nt][0]) : 0.f;
                    p1 = (krel + 1 <= qrel) ? __builtin_amdgcn_exp2f(S[nt][1]) : 0.f;
                    p2 = (krel + 2 <= qrel) ? __builtin_amdgcn_exp2f(S[nt][2]) : 0.f;
                    p3 = (krel + 3 <= qrel) ? __builtin_amdgcn_exp2f(S[nt][3]) : 0.f;
                }
                lsum += (p0 + p1) + (p2 + p3);
                uint2 pw;
                pw.x = pk2(p0, p1);
                pw.y = pk2(p2, p3);
                *(uint2*)&Ps[w][colL][((2 * nt + (quad >> 1)) ^ c7) * 8 + (quad & 1) * 4] = pw;
            }
        }

        asm volatile("s_waitcnt lgkmcnt(0)" ::: "memory");  // wave-local Ps ready
        __builtin_amdgcn_sched_barrier(0);

        // PV: static unroll, wave-uniform kb predication; swizzled chunks.
        #pragma unroll
        for (int kb = 0; kb < 2; ++kb) {
            if (kb <= kbmax) {
                const int ch = ((kb * 4 + quad) ^ c7) * 8;
                const bf16x8_t ap = frag_ld(&Ps[w][colL][ch]);
                #pragma unroll
                for (int dt = 0; dt < 4; ++dt) {
                    const bf16x8_t bv = frag_ld(&Vs[dt * 16 + colL][ch]);
                    O[dt] = __builtin_amdgcn_mfma_f32_16x16x32_bf16(ap, bv, O[dt], 0, 0, 0);
                }
            }
        }
    }

    // l partial: q = w*16 + colL; sum the 4 quads holding the same q
    {
        float sm = lsum;
        sm += __shfl_xor(sm, 16);
        sm += __shfl_xor(sm, 32);
        if (quad == 0)
            Lpart[gslot * 64 + 16 * w + colL] = sm;
    }

    // O partial (unnormalized bf16): C-layout -> per-wave LDS (swizzled) ->
    // coalesced stores
    #pragma unroll
    for (int dt = 0; dt < 4; ++dt)
        #pragma unroll
        for (int r = 0; r < 4; ++r) {
            const int row = quad * 4 + r;
            const int ch = ((2 * dt + (colL >> 3)) ^ (row & 7)) * 8 + (colL & 7);
            Ps[w][row][ch] = f2bf(O[dt][r]);
        }
    asm volatile("s_waitcnt lgkmcnt(0)" ::: "memory");
    __builtin_amdgcn_sched_barrier(0);
    #pragma unroll
    for (int p = 0; p < 2; ++p) {
        const int rowl = (L >> 3) + 8 * p;      // 0..15
        const int ch = ((L & 7) ^ (rowl & 7)) * 8;
        *(uint4*)&Opart[gslot * 4096 + (size_t)(16 * w + rowl) * 64 + (L & 7) * 8] =
            *(const uint4*)&Ps[w][rowl][ch];
    }
}

// ---------------------------------------------------------------------------
// Combine: AO[b,s,h*d] = (sum_s Opart) / (sum_s Lpart). Block = (qt, hh, bb).
// Thread t: q = t>>2, 16 d's at (t&3)*16.
// ---------------------------------------------------------------------------
__global__ __launch_bounds__(256) void combine_kernel(
    const u16* __restrict__ Opart, const float* __restrict__ Lpart,
    u16* __restrict__ AO)
{
    const int qt = blockIdx.x, hh = blockIdx.y, bb = blockIdx.z;
    const int g = qt >> 3;
    const int nsplit = g + 1;
    const int base = 4 * g * (g + 1) + (qt & 7) * (g + 1);
    const int t = threadIdx.x;
    const int q = t >> 2, dg = (t & 3) * 16;
    const size_t slot0 = (size_t)(bb * NHEADS + hh) * 80 + base;

    float acc[16];
    #pragma unroll
    for (int i = 0; i < 16; ++i) acc[i] = 0.f;
    float l = 0.f;
    for (int s = 0; s < nsplit; ++s) {
        const size_t gs = slot0 + s;
        l += Lpart[gs * 64 + q];
        const u16* op = Opart + gs * 4096 + (size_t)q * 64 + dg;
        acc8(*(const uint4*)op, acc);
        acc8(*(const uint4*)(op + 8), acc + 8);
    }
    const float inv = 1.0f / l;
    uint4 o0, o1;
    o0.x = pk2(acc[0] * inv, acc[1] * inv);  o0.y = pk2(acc[2] * inv, acc[3] * inv);
    o0.z = pk2(acc[4] * inv, acc[5] * inv);  o0.w = pk2(acc[6] * inv, acc[7] * inv);
    o1.x = pk2(acc[8] * inv, acc[9] * inv);  o1.y = pk2(acc[10] * inv, acc[11] * inv);
    o1.z = pk2(acc[12] * inv, acc[13] * inv); o1.w = pk2(acc[14] * inv, acc[15] * inv);
    u16* dst = AO + ((size_t)bb * SEQ + qt * 64 + q) * D_MODEL + hh * HDIM + dg;
    *(uint4*)dst = o0;
    *(uint4*)(dst + 8) = o1;
}

// ---------------------------------------------------------------------------
// Output projection: Out(fp32) = AO(bf16) * Wo_bf^T.
// R18: 64x128 tile, 512 blocks (2/CU), 2-phase counted vmcnt(6). Unchanged.
// ---------------------------------------------------------------------------
__global__ __launch_bounds__(256) void out_proj_kernel(
    const u16* __restrict__ A, const u16* __restrict__ Wob, float* __restrict__ Out)
{
    __shared__ __align__(16) u16 smem[24576];   // 48KB: 2 bufs x (A 64x64 | B 128x64)

    const int tid = threadIdx.x;
    const int m0 = blockIdx.y * 64;             // M = 4096 -> 64 tiles
    const int n0 = blockIdx.x * 128;            // N = 1024 -> 8 tiles

    const int w = tid >> 6, L = tid & 63, quad = L >> 4, colL = L & 15;
    const int mw = (w & 1) * 32, nw = (w >> 1) * 64;

    const int lrow = L >> 3;
    const int lchk = (L & 7) ^ lrow;            // XOR chunk swizzle

    f32x4_t acc[2][4];
    #pragma unroll
    for (int i = 0; i < 2; ++i)
        #pragma unroll
        for (int j = 0; j < 4; ++j) acc[i][j] = (f32x4_t){0.f, 0.f, 0.f, 0.f};

    // stage tile k0 into buffer boff (0 or 12288). Flat row R = 48w+8j+lrow:
    // R<64 -> A row R (at smem+boff), else B row R-64 (at smem+boff+4096).
    #define OP_STAGE(boff, k0)                                                  \
        {                                                                       \
            _Pragma("unroll")                                                   \
            for (int j = 0; j < 6; ++j) {                                       \
                const int R0 = 48 * w + 8 * j;                                  \
                const u16* src = (R0 < 64)                                      \
                    ? A + (size_t)(m0 + R0 + lrow) * D_MODEL + lchk * 8         \
                    : Wob + (size_t)(n0 + R0 - 64 + lrow) * D_MODEL + lchk * 8; \
                dma16(src + (k0), smem + (boff) + R0 * 64);                     \
            }                                                                   \
        }

    OP_STAGE(0, 0)                              // prologue: tile 0 -> buf 0
    for (int it = 0; it < 16; ++it) {
        const int boff = (it & 1) * 12288;
        if (it < 15) {
            OP_STAGE(boff ^ 12288, (it + 1) * 64)
            asm volatile("s_waitcnt vmcnt(6)" ::: "memory");  // prev stage landed
        } else {
            asm volatile("s_waitcnt vmcnt(0)" ::: "memory");
        }
        __builtin_amdgcn_sched_barrier(0);
        __builtin_amdgcn_s_barrier();
        __builtin_amdgcn_sched_barrier(0);

        const u16* a_s = smem + boff;           // A 64x64
        const u16* b_s = smem + boff + 4096;    // B 128x64
        #pragma unroll
        for (int kb = 0; kb < 2; ++kb) {
            const int ch = ((kb * 4 + quad) ^ (colL & 7)) * 8;
            bf16x8_t af[2], bf[4];
            #pragma unroll
            for (int t = 0; t < 2; ++t)
                af[t] = frag_ld(a_s + (mw + t * 16 + colL) * 64 + ch);
            #pragma unroll
            for (int t = 0; t < 4; ++t)
                bf[t] = frag_ld(b_s + (nw + t * 16 + colL) * 64 + ch);
            #pragma unroll
            for (int mt = 0; mt < 2; ++mt)
                #pragma unroll
                for (int nt = 0; nt < 4; ++nt)
                    acc[mt][nt] = __builtin_amdgcn_mfma_f32_16x16x32_bf16(
                        af[mt], bf[nt], acc[mt][nt], 0, 0, 0);
        }
        __builtin_amdgcn_s_barrier();
    }

    #pragma unroll
    for (int mt = 0; mt < 2; ++mt)
        #pragma unroll
        for (int nt = 0; nt < 4; ++nt)
            #pragma unroll
            for (int r = 0; r < 4; ++r) {
                const int m = m0 + mw + mt * 16 + quad * 4 + r;
                const int n = n0 + nw + nt * 16 + colL;
                Out[(size_t)m * D_MODEL + n] = acc[mt][nt][r];
            }
}

// ---------------------------------------------------------------------------
extern "C" void kernel_launch(void* const* d_in, const int* in_sizes, int n_in,
                              void* d_out, int out_size, void* d_ws, size_t ws_size,
                              hipStream_t stream) {
    const float* x  = (const float*)d_in[0];
    const float* wq = (const float*)d_in[1];
    const float* wk = (const float*)d_in[2];
    const float* wv = (const float*)d_in[3];
    const float* wo = (const float*)d_in[4];
    const int* pos  = (const int*)d_in[5];
    float* out = (float*)d_out;

    const size_t NELEM = (size_t)BATCH * NHEADS * SEQ * HDIM;  // 4,194,304
    u16* Qw  = (u16*)d_ws;
    u16* Kw  = Qw + NELEM;
    u16* Vtw = Kw + NELEM;
    u16* AOw = Vtw + NELEM;        // doubles as Xbf (attn writes after qkv reads)
    u16* Xbf = AOw;
    u16* Wbf = AOw + NELEM;        // 4M elems (wq|wk|wv|wo)
    u16* Opart = Wbf + NELEM;      // 2560 slots x 4096 u16 = 21MB
    float* Lpart = (float*)(Opart + (size_t)2560 * 4096);  // 2560 x 64 fp32

    conv_bf16_kernel<<<4096, 256, 0, stream>>>(x, wq, wk, wv, wo, Xbf, Wbf);
    qkv_rope_kernel<<<dim3(48, 32), 256, 0, stream>>>(Xbf, Wbf, pos, Qw, Kw, Vtw);
    attn_kernel<<<dim3(80, NHEADS, BATCH), 256, 0, stream>>>(Qw, Kw, Vtw, Opart, Lpart);
    combine_kernel<<<dim3(32, NHEADS, BATCH), 256, 0, stream>>>(Opart, Lpart, AOw);
    out_proj_kernel<<<dim3(8, 64), 256, 0, stream>>>(AOw, Wbf + 3 * (1u << 20), out);
}

// Round 12
// 180.201 us; speedup vs baseline: 1.0655x; 1.0205x over previous
//
#include <hip/hip_runtime.h>
#include <hip/hip_bf16.h>

// MultiHeadSelfAttention: B=2, S=2048, D=1024, H=16, Dh=64, RoPE theta=1e4, causal.
// Round 22: attn K/V staging -> pre-swizzled-source global_load_lds, double-
// buffered. The XOR chunk swizzle moves into the per-lane GLOBAL address
// (LDS dest linear, per G21); LDS contents identical to R21 so all frag reads
// unchanged. Removes ds_write+lgkm from the critical path, staging write
// conflicts, and 16 prefetch VGPRs. vmcnt(4) counted (never 0 mid-loop).
// LDS 24.6->40KB (4 blocks/CU). qkv(R21 128x64)/out_proj(R18)/conv/combine
// unchanged.
// ws (u16): Q|K|Vt|AO(=Xbf)|Wbf (40MB) + Opart 2560x4096 u16 (21MB) + Lpart (0.7MB).

#define D_MODEL 1024
#define NHEADS  16
#define HDIM    64
#define SEQ     2048
#define BATCH   2

typedef unsigned short u16;
typedef __bf16 bf16x8_t __attribute__((ext_vector_type(8)));
typedef float  f32x4_t  __attribute__((ext_vector_type(4)));

__device__ __forceinline__ u16 f2bf(float f) {
    union { __hip_bfloat16 h; u16 u; } cv;
    cv.h = __float2bfloat16(f);
    return cv.u;
}

__device__ __forceinline__ unsigned pk2(float x, float y) {
    union { __hip_bfloat162 h; unsigned u; } cv;
    cv.h = __float22bfloat162_rn(make_float2(x, y));   // v_cvt_pk_bf16_f32
    return cv.u;
}

__device__ __forceinline__ uint4 pack8(float4 a, float4 b) {
    uint4 u;
    u.x = pk2(a.x, a.y);
    u.y = pk2(a.z, a.w);
    u.z = pk2(b.x, b.y);
    u.w = pk2(b.z, b.w);
    return u;
}

__device__ __forceinline__ bf16x8_t frag_ld(const u16* p) {
    union { uint4 u; bf16x8_t v; } t;
    t.u = *(const uint4*)p;
    return t.v;
}

// unpack 4 bf16-pairs (uint4) -> add into 8 fp32 accumulators
__device__ __forceinline__ void acc8(uint4 u, float* a) {
    a[0] += __uint_as_float(u.x << 16); a[1] += __uint_as_float(u.x & 0xffff0000u);
    a[2] += __uint_as_float(u.y << 16); a[3] += __uint_as_float(u.y & 0xffff0000u);
    a[4] += __uint_as_float(u.z << 16); a[5] += __uint_as_float(u.z & 0xffff0000u);
    a[6] += __uint_as_float(u.w << 16); a[7] += __uint_as_float(u.w & 0xffff0000u);
}

// async global->LDS DMA, 16B/lane; LDS dest = wave-uniform base + lane*16
__device__ __forceinline__ void dma16(const u16* g, u16* l) {
    __builtin_amdgcn_global_load_lds(
        (const __attribute__((address_space(1))) void*)g,
        (__attribute__((address_space(3))) void*)l, 16, 0, 0);
}

// ---------------------------------------------------------------------------
// fp32 -> bf16 conversion: X (4M elems) -> Xbf, Wq|Wk|Wv|Wo (1M each) -> Wbf.
// ---------------------------------------------------------------------------
__global__ __launch_bounds__(256) void conv_bf16_kernel(
    const float* __restrict__ X, const float* __restrict__ Wq,
    const float* __restrict__ Wk, const float* __restrict__ Wv,
    const float* __restrict__ Wo, u16* __restrict__ Xbf, u16* __restrict__ Wbf)
{
    const size_t gid = (size_t)blockIdx.x * 256 + threadIdx.x;
    const float* src;
    u16* dst;
    size_t off;
    if (gid < (1u << 19)) {                     // X: 4M elems / 8
        src = X; dst = Xbf; off = gid;
    } else {
        size_t g = gid - (1u << 19);
        const int wsel = (int)(g >> 17);        // 1M elems / 8 per W
        g &= (1u << 17) - 1;
        src = (wsel == 0) ? Wq : (wsel == 1) ? Wk : (wsel == 2) ? Wv : Wo;
        dst = Wbf + ((size_t)wsel << 20);
        off = g;
    }
    const float4 a = *(const float4*)(src + off * 8);
    const float4 b = *(const float4*)(src + off * 8 + 4);
    *(uint4*)(dst + off * 8) = pack8(a, b);
}

// ---------------------------------------------------------------------------
// QKV projection + RoPE. R21: 128x64 tile, 48KB LDS (3 blocks/CU),
// 2-phase counted vmcnt(6). A[128][64] + B[64][64] per buffer. Unchanged.
// ---------------------------------------------------------------------------
__global__ __launch_bounds__(256) void qkv_rope_kernel(
    const u16* __restrict__ Xbf, const u16* __restrict__ Wbf,
    const int* __restrict__ pos,
    u16* __restrict__ Qo, u16* __restrict__ Ko, u16* __restrict__ Vt)
{
    __shared__ __align__(16) u16 smem[24576];   // 48KB: 2 bufs x (A 8192 | B 4096)
                                                // Ts [128][68] / [64][136] overlays
    const int tid = threadIdx.x;
    const int m0 = blockIdx.y * 128;
    const int nv = (int)blockIdx.x;             // 0..47
    const int which = nv >> 4;                  // 0=q,1=k,2=v
    const int nbase = (nv & 15) * 64;
    const u16* __restrict__ Wsrc = Wbf + ((size_t)which << 20);

    const int w = tid >> 6, L = tid & 63, quad = L >> 4, colL = L & 15;
    const int mw = (w & 1) * 64, nw = (w >> 1) * 32;

    const int lrow = L >> 3;
    const int lchk = (L & 7) ^ lrow;            // XOR chunk swizzle
    const u16* ag = Xbf + (size_t)(m0 + 32 * w + lrow) * D_MODEL + lchk * 8;
    const u16* bg = Wsrc + (size_t)(nbase + 16 * w + lrow) * D_MODEL + lchk * 8;

    f32x4_t acc[4][2];
    #pragma unroll
    for (int i = 0; i < 4; ++i)
        #pragma unroll
        for (int j = 0; j < 2; ++j) acc[i][j] = (f32x4_t){0.f, 0.f, 0.f, 0.f};

    // stage tile k0 (elems) into buffer boff (0 or 12288): A 4 dma + B 2 dma
    #define QKV_STAGE(boff, k0)                                                 \
        {                                                                       \
            u16* al = smem + (boff) + (32 * w) * 64;                            \
            u16* bl = smem + (boff) + 8192 + (16 * w) * 64;                     \
            _Pragma("unroll")                                                   \
            for (int j = 0; j < 4; ++j)                                         \
                dma16(ag + (size_t)j * 8 * D_MODEL + (k0), al + j * 512);       \
            _Pragma("unroll")                                                   \
            for (int j = 0; j < 2; ++j)                                         \
                dma16(bg + (size_t)j * 8 * D_MODEL + (k0), bl + j * 512);       \
        }

    QKV_STAGE(0, 0)                             // prologue: tile 0 -> buf 0
    for (int it = 0; it < 16; ++it) {
        const int boff = (it & 1) * 12288;      // buffer being computed
        if (it < 15) {
            QKV_STAGE(boff ^ 12288, (it + 1) * 64)  // next tile -> other buffer
            asm volatile("s_waitcnt vmcnt(6)" ::: "memory");  // prev stage landed
        } else {
            asm volatile("s_waitcnt vmcnt(0)" ::: "memory");
        }
        __builtin_amdgcn_sched_barrier(0);
        __builtin_amdgcn_s_barrier();           // all waves' stages visible
        __builtin_amdgcn_sched_barrier(0);

        const u16* a_s = smem + boff;
        const u16* b_s = smem + boff + 8192;
        #pragma unroll
        for (int kb = 0; kb < 2; ++kb) {
            const int ch = ((kb * 4 + quad) ^ (colL & 7)) * 8;
            bf16x8_t af[4], bf[2];
            #pragma unroll
            for (int t = 0; t < 4; ++t)
                af[t] = frag_ld(a_s + (mw + t * 16 + colL) * 64 + ch);
            #pragma unroll
            for (int t = 0; t < 2; ++t)
                bf[t] = frag_ld(b_s + (nw + t * 16 + colL) * 64 + ch);
            #pragma unroll
            for (int mt = 0; mt < 4; ++mt)
                #pragma unroll
                for (int nt = 0; nt < 2; ++nt)
                    acc[mt][nt] = __builtin_amdgcn_mfma_f32_16x16x32_bf16(
                        af[mt], bf[nt], acc[mt][nt], 0, 0, 0);
        }
        __builtin_amdgcn_s_barrier();           // buffer free for next stage
    }

    __syncthreads();
    u16 (*Ts)[68]  = (u16(*)[68])smem;          // q/k: [m 128][n 64]
    u16 (*Ts2)[136] = (u16(*)[136])smem;        // v:   [n 64][m 128]

    const float C0 = 0.14391156831212787f;      // ln(10000)/64
    if (which < 2) {
        // Q scale = (1/sqrt(64)) * log2(e): attn uses exp2 directly
        const float oscale = (which == 0) ? 0.18033688011112042f : 1.0f;
        float invf[2], sgn[2];
        #pragma unroll
        for (int nt = 0; nt < 2; ++nt) {
            const int n = nbase + nw + nt * 16 + colL;
            const int dd = n & 63;
            invf[nt] = __expf(-(float)(dd & 62) * C0);
            sgn[nt] = (dd & 1) ? 1.0f : -1.0f;
        }
        #pragma unroll
        for (int mt = 0; mt < 4; ++mt) {
            #pragma unroll
            for (int r = 0; r < 4; ++r) {
                const int ml = mw + mt * 16 + quad * 4 + r;
                const int ss = (m0 + ml) & 2047;
                const float p = (float)pos[ss];
                #pragma unroll
                for (int nt = 0; nt < 2; ++nt) {
                    const float v = acc[mt][nt][r];
                    const float partner = __shfl_xor(v, 1);
                    float sn, cs;
                    __sincosf(p * invf[nt], &sn, &cs);
                    Ts[ml][nw + nt * 16 + colL] =
                        f2bf((v * cs + sgn[nt] * sn * partner) * oscale);
                }
            }
        }
    } else {
        #pragma unroll
        for (int mt = 0; mt < 4; ++mt)
            #pragma unroll
            for (int nt = 0; nt < 2; ++nt)
                #pragma unroll
                for (int r = 0; r < 4; ++r)
                    Ts2[nw + nt * 16 + colL][mw + mt * 16 + quad * 4 + r] = f2bf(acc[mt][nt][r]);
    }
    __syncthreads();

    const int hh = nbase >> 6;                  // one head per block (BN=64)
    if (which < 2) {
        u16* __restrict__ dst = (which == 0) ? Qo : Ko;
        const int rr0 = tid >> 3;               // 0..31
        const int cc8 = (tid & 7) * 8;          // 0..56
        #pragma unroll
        for (int it = 0; it < 4; ++it) {
            const int ml = rr0 + it * 32;
            const int m = m0 + ml, bb = m >> 11, ss = m & 2047;
            *(uint4*)&dst[((size_t)(bb * NHEADS + hh) * SEQ + ss) * HDIM + cc8] =
                *(const uint4*)&Ts[ml][cc8];
        }
    } else {
        const int rr0 = tid >> 4;               // 0..15
        const int cc8 = (tid & 15) * 8;         // 0..120
        const int bb = m0 >> 11, ss0 = (m0 & 2047) + cc8;
        #pragma unroll
        for (int it = 0; it < 4; ++it) {
            const int nl = rr0 + it * 16;       // d = nl
            *(uint4*)&Vt[((size_t)(bb * NHEADS + hh) * HDIM + nl) * SEQ + ss0] =
                *(const uint4*)&Ts2[nl][cc8];
        }
    }
}

// ---------------------------------------------------------------------------
// Split-K flash attention (causal, max-free). Block = (slot, h, b) where slot
// encodes (qt, s): chunk s covers k-tiles [8s, min(8s+8, qt+1)). Writes
// unnormalized O partial (bf16) + l partial (fp32). 4 waves x 16 q-rows.
// Round 22: K/V staged by global_load_lds with pre-swizzled SOURCE addresses
// (LDS linear dest; contents identical to R21's swizzled layout). Double-
// buffered, counted vmcnt(4) -- next-tile DMAs never drained mid-loop.
// slot layout per (b,h): qt=8g+r has g+1 chunks; base(qt)=4g(g+1)+r(g+1); 80 total.
// ---------------------------------------------------------------------------
__global__ __launch_bounds__(256) void attn_kernel(
    const u16* __restrict__ Q, const u16* __restrict__ K,
    const u16* __restrict__ Vt, u16* __restrict__ Opart, float* __restrict__ Lpart)
{
    __shared__ __align__(16) u16 Ks[2][64][64]; // [buf][key][d], chunk-swizzled
    __shared__ __align__(16) u16 Vs[2][64][64]; // [buf][d][key], chunk-swizzled
    __shared__ __align__(16) u16 Ps[4][16][64]; // per-wave [q_local][key], swizzled

    const int tid = threadIdx.x;
    const int slot = 79 - (int)blockIdx.x;      // LPT: deepest chunks first
    const int g = (slot >= 48) ? 3 : (slot >= 24) ? 2 : (slot >= 8) ? 1 : 0;
    const int t0 = slot - 4 * g * (g + 1);
    const int rr = t0 / (g + 1);
    const int s  = t0 - rr * (g + 1);
    const int qt = 8 * g + rr;

    const int hh = blockIdx.y, bb = blockIdx.z;
    const size_t bh = ((size_t)bb * NHEADS + hh) * (SEQ * HDIM);
    const int q0 = qt * 64;
    const int kt0 = s * 8;
    const int ktend = min(kt0 + 8, qt + 1);
    const size_t gslot = ((size_t)(bb * NHEADS + hh) * 80 + slot);

    const int w = tid >> 6, L = tid & 63, quad = L >> 4, colL = L & 15;
    const int c7 = colL & 7;                    // row&7 for frag reads
    const int lr = L >> 3;                      // 0..7: row within dma slot
    const int cs = ((L & 7) ^ lr) * 8;          // pre-swizzled source chunk (elems)

    // Q fragments in registers (pre-scaled by log2e/8 in qkv): q = w*16+colL
    const u16* qp = Q + bh + (size_t)(q0 + w * 16 + colL) * HDIM + quad * 8;
    const bf16x8_t aq0 = frag_ld(qp);           // d = 0..31 slice (kb=0)
    const bf16x8_t aq1 = frag_ld(qp + 32);      // d = 32..63 slice (kb=1)

    // per-lane DMA source bases: wave w covers rows 16w..16w+15 (2 slots of 8)
    const u16* kg = K + bh + (size_t)(16 * w + lr) * HDIM + cs;
    const u16* vg = Vt + bh + (size_t)(16 * w + lr) * SEQ + cs;

    // stage tile `ktile` into buffer `buf`: LDS dest linear (wave-uniform base
    // + lane*16), swizzle folded into the per-lane global source address.
    #define ATTN_STAGE(buf, ktile)                                             \
        {                                                                      \
            const size_t ko = (size_t)(ktile) * (64 * HDIM);                   \
            const size_t vo = (size_t)(ktile) * 64;                            \
            dma16(kg + ko,            &Ks[buf][16 * w][0]);                    \
            dma16(kg + ko + 8 * HDIM, &Ks[buf][16 * w + 8][0]);                \
            dma16(vg + vo,            &Vs[buf][16 * w][0]);                    \
            dma16(vg + vo + 8 * SEQ,  &Vs[buf][16 * w + 8][0]);                \
        }

    float lsum = 0.f;                           // per-lane, q = w*16 + colL
    f32x4_t O[4];
    #pragma unroll
    for (int dt = 0; dt < 4; ++dt) O[dt] = (f32x4_t){0.f, 0.f, 0.f, 0.f};

    ATTN_STAGE(0, kt0)                          // prologue: first tile -> buf 0

    for (int kt = kt0; kt < ktend; ++kt) {
        const int buf = kt & 1;                 // kt0 even -> buf 0 first
        __builtin_amdgcn_s_barrier();           // all waves done reading buf^1
        if (kt + 1 < ktend) {
            ATTN_STAGE(buf ^ 1, kt + 1)         // next tile; stays in flight
            asm volatile("s_waitcnt vmcnt(4)" ::: "memory");  // THIS tile landed
        } else {
            asm volatile("s_waitcnt vmcnt(0)" ::: "memory");
        }
        __builtin_amdgcn_sched_barrier(0);
        __builtin_amdgcn_s_barrier();           // buf complete block-wide
        __builtin_amdgcn_sched_barrier(0);

        const bool diag = (kt == qt);
        const int ntmax = diag ? w : 3;         // wave-uniform causal pruning
        const int kbmax = diag ? (w >> 1) : 1;

        // S^T = K·Q^T: S[nt][r] = score(key = nt*16+quad*4+r, q = w*16+colL)
        // swizzled chunks: kb0 -> quad^c7, kb1 -> (quad^4)^c7
        f32x4_t S[4];
        #pragma unroll
        for (int nt = 0; nt < 4; ++nt) S[nt] = (f32x4_t){0.f, 0.f, 0.f, 0.f};
        #pragma unroll
        for (int nt = 0; nt < 4; ++nt) {
            if (nt <= ntmax) {
                S[nt] = __builtin_amdgcn_mfma_f32_16x16x32_bf16(
                    frag_ld(&Ks[buf][nt * 16 + colL][(quad ^ c7) * 8]), aq0, S[nt], 0, 0, 0);
                S[nt] = __builtin_amdgcn_mfma_f32_16x16x32_bf16(
                    frag_ld(&Ks[buf][nt * 16 + colL][((quad ^ 4) ^ c7) * 8]), aq1, S[nt], 0, 0, 0);
            }
        }

        // max-free: p = exp2(s) (log2e pre-folded); lane holds 4 consecutive
        // keys per nt => pack pairs, one ds_write_b64 per nt (swizzled chunk).
        if (!diag) {                            // clean path: no masking (94% of tiles)
            #pragma unroll
            for (int nt = 0; nt < 4; ++nt) {
                const float p0 = __builtin_amdgcn_exp2f(S[nt][0]);
                const float p1 = __builtin_amdgcn_exp2f(S[nt][1]);
                const float p2 = __builtin_amdgcn_exp2f(S[nt][2]);
                const float p3 = __builtin_amdgcn_exp2f(S[nt][3]);
                lsum += (p0 + p1) + (p2 + p3);
                uint2 pw;
                pw.x = pk2(p0, p1);
                pw.y = pk2(p2, p3);
                *(uint2*)&Ps[w][colL][((2 * nt + (quad >> 1)) ^ c7) * 8 + (quad & 1) * 4] = pw;
            }
        } else {
            const int qrel = w * 16 + colL;     // q - qt*64
            #pragma unroll
            for (int nt = 0; nt < 4; ++nt) {
                float p0 = 0.f, p1 = 0.f, p2 = 0.f, p3 = 0.f;
                if (nt <= ntmax) {              // wave-uniform scalar branch
                    const int krel = nt * 16 + quad * 4;
                    p0 = (krel + 0 <= qrel) ? __builtin_amdgcn_exp2f(S[nt][0]) : 0.f;
                    p1 = (krel + 1 <= qrel) ? __builtin_amdgcn_exp2f(S[nt][1]) : 0.f;
                    p2 = (krel + 2 <= qrel) ? __builtin_amdgcn_exp2f(S[nt][2]) : 0.f;
                    p3 = (krel + 3 <= qrel) ? __builtin_amdgcn_exp2f(S[nt][3]) : 0.f;
                }
                lsum += (p0 + p1) + (p2 + p3);
                uint2 pw;
                pw.x = pk2(p0, p1);
                pw.y = pk2(p2, p3);
                *(uint2*)&Ps[w][colL][((2 * nt + (quad >> 1)) ^ c7) * 8 + (quad & 1) * 4] = pw;
            }
        }

        asm volatile("s_waitcnt lgkmcnt(0)" ::: "memory");  // wave-local Ps ready
        __builtin_amdgcn_sched_barrier(0);

        // PV: static unroll, wave-uniform kb predication; swizzled chunks.
        #pragma unroll
        for (int kb = 0; kb < 2; ++kb) {
            if (kb <= kbmax) {
                const int ch = ((kb * 4 + quad) ^ c7) * 8;
                const bf16x8_t ap = frag_ld(&Ps[w][colL][ch]);
                #pragma unroll
                for (int dt = 0; dt < 4; ++dt) {
                    const bf16x8_t bv = frag_ld(&Vs[buf][dt * 16 + colL][ch]);
                    O[dt] = __builtin_amdgcn_mfma_f32_16x16x32_bf16(ap, bv, O[dt], 0, 0, 0);
                }
            }
        }
    }

    // l partial: q = w*16 + colL; sum the 4 quads holding the same q
    {
        float sm = lsum;
        sm += __shfl_xor(sm, 16);
        sm += __shfl_xor(sm, 32);
        if (quad == 0)
            Lpart[gslot * 64 + 16 * w + colL] = sm;
    }

    // O partial (unnormalized bf16): C-layout -> per-wave LDS (swizzled) ->
    // coalesced stores
    #pragma unroll
    for (int dt = 0; dt < 4; ++dt)
        #pragma unroll
        for (int r = 0; r < 4; ++r) {
            const int row = quad * 4 + r;
            const int ch = ((2 * dt + (colL >> 3)) ^ (row & 7)) * 8 + (colL & 7);
            Ps[w][row][ch] = f2bf(O[dt][r]);
        }
    asm volatile("s_waitcnt lgkmcnt(0)" ::: "memory");
    __builtin_amdgcn_sched_barrier(0);
    #pragma unroll
    for (int p = 0; p < 2; ++p) {
        const int rowl = (L >> 3) + 8 * p;      // 0..15
        const int ch = ((L & 7) ^ (rowl & 7)) * 8;
        *(uint4*)&Opart[gslot * 4096 + (size_t)(16 * w + rowl) * 64 + (L & 7) * 8] =
            *(const uint4*)&Ps[w][rowl][ch];
    }
}

// ---------------------------------------------------------------------------
// Combine: AO[b,s,h*d] = (sum_s Opart) / (sum_s Lpart). Block = (qt, hh, bb).
// Thread t: q = t>>2, 16 d's at (t&3)*16.
// ---------------------------------------------------------------------------
__global__ __launch_bounds__(256) void combine_kernel(
    const u16* __restrict__ Opart, const float* __restrict__ Lpart,
    u16* __restrict__ AO)
{
    const int qt = blockIdx.x, hh = blockIdx.y, bb = blockIdx.z;
    const int g = qt >> 3;
    const int nsplit = g + 1;
    const int base = 4 * g * (g + 1) + (qt & 7) * (g + 1);
    const int t = threadIdx.x;
    const int q = t >> 2, dg = (t & 3) * 16;
    const size_t slot0 = (size_t)(bb * NHEADS + hh) * 80 + base;

    float acc[16];
    #pragma unroll
    for (int i = 0; i < 16; ++i) acc[i] = 0.f;
    float l = 0.f;
    for (int s = 0; s < nsplit; ++s) {
        const size_t gs = slot0 + s;
        l += Lpart[gs * 64 + q];
        const u16* op = Opart + gs * 4096 + (size_t)q * 64 + dg;
        acc8(*(const uint4*)op, acc);
        acc8(*(const uint4*)(op + 8), acc + 8);
    }
    const float inv = 1.0f / l;
    uint4 o0, o1;
    o0.x = pk2(acc[0] * inv, acc[1] * inv);  o0.y = pk2(acc[2] * inv, acc[3] * inv);
    o0.z = pk2(acc[4] * inv, acc[5] * inv);  o0.w = pk2(acc[6] * inv, acc[7] * inv);
    o1.x = pk2(acc[8] * inv, acc[9] * inv);  o1.y = pk2(acc[10] * inv, acc[11] * inv);
    o1.z = pk2(acc[12] * inv, acc[13] * inv); o1.w = pk2(acc[14] * inv, acc[15] * inv);
    u16* dst = AO + ((size_t)bb * SEQ + qt * 64 + q) * D_MODEL + hh * HDIM + dg;
    *(uint4*)dst = o0;
    *(uint4*)(dst + 8) = o1;
}

// ---------------------------------------------------------------------------
// Output projection: Out(fp32) = AO(bf16) * Wo_bf^T.
// R18: 64x128 tile, 512 blocks (2/CU), 2-phase counted vmcnt(6). Unchanged.
// ---------------------------------------------------------------------------
__global__ __launch_bounds__(256) void out_proj_kernel(
    const u16* __restrict__ A, const u16* __restrict__ Wob, float* __restrict__ Out)
{
    __shared__ __align__(16) u16 smem[24576];   // 48KB: 2 bufs x (A 64x64 | B 128x64)

    const int tid = threadIdx.x;
    const int m0 = blockIdx.y * 64;             // M = 4096 -> 64 tiles
    const int n0 = blockIdx.x * 128;            // N = 1024 -> 8 tiles

    const int w = tid >> 6, L = tid & 63, quad = L >> 4, colL = L & 15;
    const int mw = (w & 1) * 32, nw = (w >> 1) * 64;

    const int lrow = L >> 3;
    const int lchk = (L & 7) ^ lrow;            // XOR chunk swizzle

    f32x4_t acc[2][4];
    #pragma unroll
    for (int i = 0; i < 2; ++i)
        #pragma unroll
        for (int j = 0; j < 4; ++j) acc[i][j] = (f32x4_t){0.f, 0.f, 0.f, 0.f};

    // stage tile k0 into buffer boff (0 or 12288). Flat row R = 48w+8j+lrow:
    // R<64 -> A row R (at smem+boff), else B row R-64 (at smem+boff+4096).
    #define OP_STAGE(boff, k0)                                                  \
        {                                                                       \
            _Pragma("unroll")                                                   \
            for (int j = 0; j < 6; ++j) {                                       \
                const int R0 = 48 * w + 8 * j;                                  \
                const u16* src = (R0 < 64)                                      \
                    ? A + (size_t)(m0 + R0 + lrow) * D_MODEL + lchk * 8         \
                    : Wob + (size_t)(n0 + R0 - 64 + lrow) * D_MODEL + lchk * 8; \
                dma16(src + (k0), smem + (boff) + R0 * 64);                     \
            }                                                                   \
        }

    OP_STAGE(0, 0)                              // prologue: tile 0 -> buf 0
    for (int it = 0; it < 16; ++it) {
        const int boff = (it & 1) * 12288;
        if (it < 15) {
            OP_STAGE(boff ^ 12288, (it + 1) * 64)
            asm volatile("s_waitcnt vmcnt(6)" ::: "memory");  // prev stage landed
        } else {
            asm volatile("s_waitcnt vmcnt(0)" ::: "memory");
        }
        __builtin_amdgcn_sched_barrier(0);
        __builtin_amdgcn_s_barrier();
        __builtin_amdgcn_sched_barrier(0);

        const u16* a_s = smem + boff;           // A 64x64
        const u16* b_s = smem + boff + 4096;    // B 128x64
        #pragma unroll
        for (int kb = 0; kb < 2; ++kb) {
            const int ch = ((kb * 4 + quad) ^ (colL & 7)) * 8;
            bf16x8_t af[2], bf[4];
            #pragma unroll
            for (int t = 0; t < 2; ++t)
                af[t] = frag_ld(a_s + (mw + t * 16 + colL) * 64 + ch);
            #pragma unroll
            for (int t = 0; t < 4; ++t)
                bf[t] = frag_ld(b_s + (nw + t * 16 + colL) * 64 + ch);
            #pragma unroll
            for (int mt = 0; mt < 2; ++mt)
                #pragma unroll
                for (int nt = 0; nt < 4; ++nt)
                    acc[mt][nt] = __builtin_amdgcn_mfma_f32_16x16x32_bf16(
                        af[mt], bf[nt], acc[mt][nt], 0, 0, 0);
        }
        __builtin_amdgcn_s_barrier();
    }

    #pragma unroll
    for (int mt = 0; mt < 2; ++mt)
        #pragma unroll
        for (int nt = 0; nt < 4; ++nt)
            #pragma unroll
            for (int r = 0; r < 4; ++r) {
                const int m = m0 + mw + mt * 16 + quad * 4 + r;
                const int n = n0 + nw + nt * 16 + colL;
                Out[(size_t)m * D_MODEL + n] = acc[mt][nt][r];
            }
}

// ---------------------------------------------------------------------------
extern "C" void kernel_launch(void* const* d_in, const int* in_sizes, int n_in,
                              void* d_out, int out_size, void* d_ws, size_t ws_size,
                              hipStream_t stream) {
    const float* x  = (const float*)d_in[0];
    const float* wq = (const float*)d_in[1];
    const float* wk = (const float*)d_in[2];
    const float* wv = (const float*)d_in[3];
    const float* wo = (const float*)d_in[4];
    const int* pos  = (const int*)d_in[5];
    float* out = (float*)d_out;

    const size_t NELEM = (size_t)BATCH * NHEADS * SEQ * HDIM;  // 4,194,304
    u16* Qw  = (u16*)d_ws;
    u16* Kw  = Qw + NELEM;
    u16* Vtw = Kw + NELEM;
    u16* AOw = Vtw + NELEM;        // doubles as Xbf (attn writes after qkv reads)
    u16* Xbf = AOw;
    u16* Wbf = AOw + NELEM;        // 4M elems (wq|wk|wv|wo)
    u16* Opart = Wbf + NELEM;      // 2560 slots x 4096 u16 = 21MB
    float* Lpart = (float*)(Opart + (size_t)2560 * 4096);  // 2560 x 64 fp32

    conv_bf16_kernel<<<4096, 256, 0, stream>>>(x, wq, wk, wv, wo, Xbf, Wbf);
    qkv_rope_kernel<<<dim3(48, 32), 256, 0, stream>>>(Xbf, Wbf, pos, Qw, Kw, Vtw);
    attn_kernel<<<dim3(80, NHEADS, BATCH), 256, 0, stream>>>(Qw, Kw, Vtw, Opart, Lpart);
    combine_kernel<<<dim3(32, NHEADS, BATCH), 256, 0, stream>>>(Opart, Lpart, AOw);
    out_proj_kernel<<<dim3(8, 64), 256, 0, stream>>>(AOw, Wbf + 3 * (1u << 20), out);
}